// Round 6
// baseline (256.413 us; speedup 1.0000x reference)
//
#include <hip/hip_runtime.h>

// Gridding R6: wave-aggregated direct-to-global binning (p1) + R5's packed
// u64 LDS-atomic accumulation (p2, unchanged — it sits exactly on the LDS
// atomic-pipe floor: 16.8M lane-atomics x 3.25cyc / 256 CU = 88 us).
//
// p1 redesign rationale (R5 post-mortem): old p1 (~100 us) funneled 64
// lanes into 16 same-address LDS counters (serialized RMW) and flushed all
// CCAP slots (101 MB). Now: per wave, one __ballot per slab -> count+rank;
// leader lane does the single counter atomicAdd; lanes store payload
// directly to global at base+rank (runs of ~4 consecutive slots per slab).
// No staging arrays, no full-capacity flush, 5.24M -> ~1.6M atomic lane-ops.

#define NPTS   65536
#define NCHUNK 32
#define CHSZ   2048
#define NSLAB  16
#define SLABW  4
#define CCAP   256
#define SLOTS  (NCHUNK * CCAP)     // 8192 slots per bucket
#define ACCN   16384               // 2 planes * 64 * 64 u32
#define QSCALE 262144.0f           // 2^18
#define QINV   (1.0f / 262144.0f)

// ---------------- Phase 1: wave-aggregated binning ----------------
__global__ __launch_bounds__(512) void p1_bin(
    const float* __restrict__ pt,
    float* __restrict__ gx, float* __restrict__ gy, float* __restrict__ gz,
    int* __restrict__ bcnt)
{
    __shared__ int cnt[NSLAB];
    if (threadIdx.x < NSLAB) cnt[threadIdx.x] = 0;
    __syncthreads();

    const int blk = blockIdx.x;          // B*NCHUNK
    const int b = blk >> 5;
    const int c = blk & 31;
    const float* p = pt + ((size_t)b * NPTS + (size_t)c * CHSZ) * 3;
    const int lane = threadIdx.x & 63;
    const unsigned long long lt_mask = (lane == 63) ? 0x7fffffffffffffffull
                                                    : ((1ull << lane) - 1ull);

    #pragma unroll
    for (int k = 0; k < CHSZ / 512; ++k) {
        int li = k * 512 + threadIdx.x;
        float px = p[3 * li + 0] * 32.0f;   // *32 exact in fp32
        float py = p[3 * li + 1] * 32.0f;
        float pz = p[3 * li + 2] * 32.0f;

        bool nz = (fabsf(px) + fabsf(py) + fabsf(pz)) != 0.0f;  // nz_mask
        int ix = (int)floorf(px) + 32;
        bool valid = nz && ((unsigned)ix <= 63u);
        int s0 = valid ? (ix >> 2) : -1;
        int s1 = (valid && (ix & 3) == 3 && ix < 63) ? (s0 + 1) : -1;

        int slot0 = -1, slot1 = -1;

        #pragma unroll
        for (int s = 0; s < NSLAB; ++s) {
            // round A: primary slab
            unsigned long long m = __ballot(s0 == s);
            if (m) {
                int leader = __ffsll((long long)m) - 1;
                int base = 0;
                if (lane == leader) base = atomicAdd(&cnt[s], __popcll(m));
                base = __shfl(base, leader, 64);
                int pos = base + __popcll(m & lt_mask);
                if (s0 == s && pos < CCAP)
                    slot0 = ((b * NSLAB + s) * NCHUNK + c) * CCAP + pos;
            }
            // round B: duplicate (x+1 straddles into next slab)
            unsigned long long m2 = __ballot(s1 == s);
            if (m2) {
                int leader = __ffsll((long long)m2) - 1;
                int base = 0;
                if (lane == leader) base = atomicAdd(&cnt[s], __popcll(m2));
                base = __shfl(base, leader, 64);
                int pos = base + __popcll(m2 & lt_mask);
                if (s1 == s && pos < CCAP)
                    slot1 = ((b * NSLAB + s) * NCHUNK + c) * CCAP + pos;
            }
        }

        if (slot0 >= 0) { gx[slot0] = px; gy[slot0] = py; gz[slot0] = pz; }
        if (slot1 >= 0) { gx[slot1] = px; gy[slot1] = py; gz[slot1] = pz; }
    }
    __syncthreads();
    if (threadIdx.x < NSLAB)
        bcnt[(b * NSLAB + threadIdx.x) * NCHUNK + c] = min(cnt[threadIdx.x], CCAP);
}

// ---------------- Phase 2: 2-plane sub-slab, packed u64 LDS atomics -------
__global__ __launch_bounds__(1024) void p2_accum(
    const float* __restrict__ gx, const float* __restrict__ gy,
    const float* __restrict__ gz, const int* __restrict__ bcnt,
    float* __restrict__ out)
{
    // S[0..ACCN)      = A: cell (xl,y,z) at (xl*64+y)*64+z   (z-even u64 pairs)
    // S[ACCN..2*ACCN) = B: shifted pairs for z-odd           (both 8B-aligned)
    __shared__ unsigned int S[2 * ACCN];

    const int pb = blockIdx.x >> 1;     // parent bucket (b*16 + s)
    const int h  = blockIdx.x & 1;
    const int b  = pb >> 4;
    const int s  = pb & 15;
    const int x0 = s * SLABW + h * 2;   // my 2 planes

    uint4* s4 = (uint4*)S;
    #pragma unroll
    for (int i = threadIdx.x; i < (2 * ACCN) / 4; i += 1024)
        s4[i] = make_uint4(0u, 0u, 0u, 0u);
    __syncthreads();

    const size_t base = (size_t)pb * SLOTS;
    const int* myc = bcnt + pb * NCHUNK;

    #pragma unroll
    for (int t = threadIdx.x; t < SLOTS; t += 1024) {
        int c = t >> 8;                 // CCAP = 256
        int pos = t & 255;
        if (pos >= myc[c]) continue;

        float px = gx[base + t];
        float py = gy[base + t];
        float pz = gz[base + t];

        float lx = floorf(px), ly = floorf(py), lz = floorf(pz);
        float fx = px - lx,    fy = py - ly,    fz = pz - lz;
        int ix = (int)lx + 32, iy = (int)ly + 32, iz = (int)lz + 32;
        if ((unsigned)iz > 63u) continue;

        float wx[2] = {1.0f - fx, fx};
        float wy[2] = {1.0f - fy, fy};
        float wz0 = 1.0f - fz, wz1 = fz;

        const int odd = iz & 1;
        const int zoff = odd ? (ACCN + iz - 1) : iz;
        const bool hi_ok = (iz != 63);

        #pragma unroll
        for (int di = 0; di < 2; ++di) {
            int xl = ix + di - x0;
            if ((unsigned)xl >= 2u) continue;
            #pragma unroll
            for (int dj = 0; dj < 2; ++dj) {
                int yy = iy + dj;
                if ((unsigned)yy >= 64u) continue;
                float wxy = wx[di] * wy[dj];
                unsigned int q0 = __float2uint_rn(wxy * wz0 * QSCALE);
                unsigned int q1 = hi_ok ? __float2uint_rn(wxy * wz1 * QSCALE) : 0u;
                int cb = (xl * 64 + yy) * 64;
                unsigned long long pk =
                    (unsigned long long)q0 | ((unsigned long long)q1 << 32);
                atomicAdd((unsigned long long*)&S[cb + zoff], pk);  // ds_add_u64
            }
        }
    }
    __syncthreads();

    float* o = out + ((size_t)b * 64 + x0) * 4096;
    #pragma unroll
    for (int i = threadIdx.x; i < 2 * 4096; i += 1024) {
        int z = i & 63;
        unsigned int v = S[i] + (z ? S[ACCN + i - 1] : 0u);
        o[i] = (float)v * QINV;
    }
}

// ---- Fallback (R2 exclusive-slab redundant scan) if workspace too small.
__global__ __launch_bounds__(1024) void gridding_slab(
    const float* __restrict__ pt, float* __restrict__ out)
{
    __shared__ float lds[SLABW * 64 * 64];
    const int blk = blockIdx.x;
    const int b   = blk >> 4;
    const int x0  = (blk & 15) * SLABW;
    float4* l4 = (float4*)lds;
    #pragma unroll
    for (int i = threadIdx.x; i < (SLABW * 64 * 64) / 4; i += 1024)
        l4[i] = make_float4(0.f, 0.f, 0.f, 0.f);
    __syncthreads();
    const float* p = pt + (size_t)b * NPTS * 3;
    for (int it = 0; it < NPTS / 1024; ++it) {
        int i = it * 1024 + threadIdx.x;
        float px = p[3 * i + 0] * 32.0f;
        float py = p[3 * i + 1] * 32.0f;
        float pz = p[3 * i + 2] * 32.0f;
        if (fabsf(px) + fabsf(py) + fabsf(pz) == 0.0f) continue;
        float lx = floorf(px), ly = floorf(py), lz = floorf(pz);
        float fx = px - lx, fy = py - ly, fz = pz - lz;
        int ix = (int)lx + 32, iy = (int)ly + 32, iz = (int)lz + 32;
        float wx[2] = {1.0f - fx, fx};
        float wy[2] = {1.0f - fy, fy};
        float wz[2] = {1.0f - fz, fz};
        #pragma unroll
        for (int di = 0; di < 2; ++di) {
            int xl = (ix + di) - x0;
            if ((unsigned)xl >= SLABW) continue;
            #pragma unroll
            for (int dj = 0; dj < 2; ++dj) {
                int yy = iy + dj;
                if ((unsigned)yy >= 64u) continue;
                float wxy = wx[di] * wy[dj];
                int basei = (xl * 64 + yy) * 64;
                #pragma unroll
                for (int dk = 0; dk < 2; ++dk) {
                    int zz = iz + dk;
                    if ((unsigned)zz >= 64u) continue;
                    atomicAdd(&lds[basei + zz], wxy * wz[dk]);
                }
            }
        }
    }
    __syncthreads();
    float4* o4 = (float4*)(out + ((size_t)b * 64 + x0) * 4096);
    #pragma unroll
    for (int i = threadIdx.x; i < (SLABW * 64 * 64) / 4; i += 1024)
        o4[i] = l4[i];
}

extern "C" void kernel_launch(void* const* d_in, const int* in_sizes, int n_in,
                              void* d_out, int out_size, void* d_ws, size_t ws_size,
                              hipStream_t stream) {
    const float* pt = (const float*)d_in[0];
    float* out = (float*)d_out;
    const int B = (in_sizes[0] / 3) / NPTS;   // 64

    const size_t nbuck = (size_t)B * NSLAB;           // 1024
    const size_t arr   = nbuck * SLOTS;
    const size_t need  = 3 * arr * sizeof(float) + nbuck * NCHUNK * sizeof(int);

    if (ws_size >= need) {
        float* gx = (float*)d_ws;
        float* gy = gx + arr;
        float* gz = gy + arr;
        int* bcnt = (int*)(gz + arr);
        p1_bin<<<B * NCHUNK, 512, 0, stream>>>(pt, gx, gy, gz, bcnt);
        p2_accum<<<(int)(nbuck * 2), 1024, 0, stream>>>(gx, gy, gz, bcnt, out);
    } else {
        gridding_slab<<<B * NSLAB, 1024, 0, stream>>>(pt, out);
    }
}